// Round 8
// baseline (100.021 us; speedup 1.0000x reference)
//
#include <hip/hip_runtime.h>

#define FEAT 2048
#define HWD 14
#define NPIX 196          // 14*14
#define C_CLS 20
#define M_DIM 64
#define U_DIM 128
#define B_SZ 4
#define K_REL 19          // C-1
#define NPOOL 49          // 7*7

typedef __attribute__((ext_vector_type(8))) short bf16x8s;
typedef __attribute__((ext_vector_type(8))) unsigned short ushort8v;
typedef __attribute__((ext_vector_type(4))) float f32x4;
typedef __attribute__((ext_vector_type(4))) unsigned int uint4v;

__device__ inline unsigned short f2bf(float f) {
    unsigned u = __builtin_bit_cast(unsigned, f);
    unsigned r = (u + 0x7FFF + ((u >> 16) & 1)) >> 16;   // RNE
    return (unsigned short)r;
}

__device__ inline bf16x8s cvt8(const float* __restrict__ p) {
    float4 lo = *(const float4*)p;
    float4 hi = *(const float4*)(p + 4);
    bf16x8s r;
    r[0] = (short)f2bf(lo.x); r[1] = (short)f2bf(lo.y);
    r[2] = (short)f2bf(lo.z); r[3] = (short)f2bf(lo.w);
    r[4] = (short)f2bf(hi.x); r[5] = (short)f2bf(hi.y);
    r[6] = (short)f2bf(hi.z); r[7] = (short)f2bf(hi.w);
    return r;
}

// ---------------------------------------------------------------------------
// Kernel 1: prep.
//  blocks 0..127 (b = blk>>5, s = blk&31): x[b][s*64..+63][hw] ->
//     xts[b][s][i=ch*208+row][8]   (B-fragment order; row>=196 -> 0)
//  blocks 128..287: Awp[c*256 + s*8 + fi][lane][8]  (A-fragment order, bf16)
// ---------------------------------------------------------------------------
__global__ __launch_bounds__(256) void prep_kernel(
        const float* __restrict__ x, const float* __restrict__ Wp,
        unsigned short* __restrict__ xts, unsigned short* __restrict__ Awp) {
    __shared__ unsigned short T[64][210];
    const int blk = blockIdx.x;
    const int tid = threadIdx.x;
    if (blk < 128) {
        const int b = blk >> 5;
        const int s = blk & 31;
        const float* xb = x + ((size_t)b * FEAT + s * 64) * NPIX;
        for (int i = tid; i < 64 * NPIX; i += 256) {
            int kk = i / NPIX, hw = i - kk * NPIX;
            T[kk][hw] = f2bf(xb[(size_t)kk * NPIX + hw]);
        }
        __syncthreads();
        unsigned short* ob = xts + ((size_t)(b * 32 + s)) * 1664 * 8;
        for (int i = tid; i < 1664; i += 256) {
            int ch = i / 208, row = i - ch * 208;
            ushort8v o;
#pragma unroll
            for (int j = 0; j < 8; j++)
                o[j] = (row < NPIX) ? T[ch * 8 + j][row] : (unsigned short)0;
            *(ushort8v*)(ob + (size_t)i * 8) = o;
        }
    } else {
        const int lane = tid & 63;
        // Awp: 5120 rows (c:20 x s:32 x fi:8), one row per wave, 640 waves
        int gw = (blk - 128) * 4 + (tid >> 6);
        for (int r = gw; r < 5120; r += 160 * 4) {
            int c = r >> 8;
            int rem = r & 255;
            int s = rem >> 3, fi = rem & 7;
            int rt = fi >> 1, f = fi & 1;
            int m = rt * 16 + (lane & 15);
            int k = s * 64 + f * 32 + (lane >> 4) * 8;
            bf16x8s v = cvt8(Wp + ((size_t)(c * M_DIM + m)) * FEAT + k);
            *(bf16x8s*)(Awp + ((size_t)r * 64 + lane) * 8) = v;
        }
    }
}

// ---------------------------------------------------------------------------
// Kernel 2: GEMM, K-split 4. Block=(c,b,ks): 64x208 x K=512 slice.
// 4 waves = pure column split, col-tiles {4,3,3,3}. No LDS, no barriers;
// A/B fragments direct from pre-swizzled global, depth-1 named prefetch.
// Writes fp32 partial xsp[ks][b][c][64][208] (no atomics).
// ---------------------------------------------------------------------------
__global__ __launch_bounds__(256) void gemm_kernel(
        const unsigned short* __restrict__ xts,
        const unsigned short* __restrict__ Awp,
        float* __restrict__ xsp) {
    const int c = blockIdx.x, b = blockIdx.y, ks = blockIdx.z;
    const int tid = threadIdx.x;
    const int lane = tid & 63, wv = tid >> 6;
    const int l15 = lane & 15, lq = lane >> 4;
    const int t0 = (wv == 0) ? 0 : (3 * wv + 1);   // {0,4,7,10}
    const int nt = (wv == 0) ? 4 : 3;

    const unsigned short* xsrc = xts + (size_t)b * 32 * 1664 * 8;
    const unsigned short* asrc = Awp + (size_t)c * 256 * 64 * 8;
    const int s0 = ks * 8;

    bf16x8s A0[8], A1[8], B0[8], B1[8];
    auto aload = [&](int s, bf16x8s (&A)[8]) {
#pragma unroll
        for (int fi = 0; fi < 8; fi++)
            A[fi] = *(const bf16x8s*)(asrc + (((size_t)s * 8 + fi) * 64 + lane) * 8);
    };
    auto bload = [&](int s, bf16x8s (&B)[8]) {
#pragma unroll
        for (int q = 0; q < 4; q++) {
            if (q < nt) {
#pragma unroll
                for (int f = 0; f < 2; f++)
                    B[q * 2 + f] = *(const bf16x8s*)(xsrc +
                        ((size_t)s * 1664 + (f * 4 + lq) * 208 + (t0 + q) * 16 + l15) * 8);
            }
        }
    };

    f32x4 acc[4][4];   // [col-tile q][row-frag rt]
#pragma unroll
    for (int q = 0; q < 4; q++)
#pragma unroll
        for (int rt = 0; rt < 4; rt++) acc[q][rt] = (f32x4){0.f, 0.f, 0.f, 0.f};

    auto compute = [&](bf16x8s (&A)[8], bf16x8s (&B)[8]) {
#pragma unroll
        for (int q = 0; q < 4; q++) {
            if (q < nt) {
#pragma unroll
                for (int rt = 0; rt < 4; rt++)
#pragma unroll
                    for (int f = 0; f < 2; f++)
                        acc[q][rt] = __builtin_amdgcn_mfma_f32_16x16x32_bf16(
                            A[rt * 2 + f], B[q * 2 + f], acc[q][rt], 0, 0, 0);
            }
        }
    };

    aload(s0, A0); bload(s0, B0);
#pragma unroll
    for (int sp = 0; sp < 4; sp++) {
        aload(s0 + 2 * sp + 1, A1); bload(s0 + 2 * sp + 1, B1);
        compute(A0, B0);
        if (sp < 3) { aload(s0 + 2 * sp + 2, A0); bload(s0 + 2 * sp + 2, B0); }
        compute(A1, B1);
    }

    float* ob = xsp + ((size_t)(ks * B_SZ + b) * C_CLS + c) * 64 * 208;
#pragma unroll
    for (int q = 0; q < 4; q++) {
        if (q < nt) {
            int tt = t0 + q;
#pragma unroll
            for (int rt = 0; rt < 4; rt++)
#pragma unroll
                for (int r = 0; r < 4; r++)
                    ob[(rt * 16 + lq * 4 + r) * 208 + tt * 16 + l15] = acc[q][rt][r];
        }
    }
}

// ---------------------------------------------------------------------------
// Kernel 3: phases. Block=(c,b), 512 thr. Sum 4 K-partials -> xs LDS,
// then pool -> theta -> bilinear sample -> x_objT (208 rows, 196..207 = 0).
// ---------------------------------------------------------------------------
__global__ __launch_bounds__(512) void phases_kernel(
        const float* __restrict__ xsp,
        const float* __restrict__ Wstn,
        const float* __restrict__ bstn,
        unsigned short* __restrict__ x_objT) {
    __shared__ __align__(16) char smem[78336];
    float* xs     = (float*)smem;              // [64][209] = 53,504 B
    float* pooled = (float*)(smem + 53504);    // [3136]    = 12,544 B
    float* red    = (float*)(smem + 66048);    // [6][512]  = 12,288 B

    const int c = blockIdx.x, b = blockIdx.y;
    const int tid = threadIdx.x;

    // sum 4 K-split partials
    const size_t S = (size_t)B_SZ * C_CLS * 13312;   // per-ks stride
    const float* pb = xsp + (size_t)(b * C_CLS + c) * 13312;
#pragma unroll 2
    for (int it = 0; it < 26; it++) {
        int i = tid + it * 512;                      // 26*512 = 13312 exact
        float v = pb[i] + pb[i + S] + pb[i + 2 * S] + pb[i + 3 * S];
        xs[(i / 208) * 209 + (i % 208)] = v;
    }
    __syncthreads();

    // pool
    for (int i = tid; i < 3136; i += 512) {
        int m = i / NPOOL, p = i - m * NPOOL;
        int ph = p / 7, pw = p - ph * 7;
        const float* bp = &xs[m * 209 + ph * 2 * HWD + pw * 2];
        float v = fmaxf(fmaxf(bp[0], bp[1]), fmaxf(bp[HWD], bp[HWD + 1]));
        pooled[i] = fmaxf(v, 0.f);
    }
    __syncthreads();

    // theta
    float sj[6] = {0, 0, 0, 0, 0, 0};
#pragma unroll
    for (int it = 0; it < 7; it++) {
        int kk = tid + it * 512;
        if (kk < 3136) {
            float f = pooled[kk];
#pragma unroll
            for (int j = 0; j < 6; j++)
                sj[j] += f * Wstn[((size_t)c * 6 + j) * 3136 + kk];
        }
    }
#pragma unroll
    for (int j = 0; j < 6; j++) red[j * 512 + tid] = sj[j];
    __syncthreads();
    for (int off = 256; off > 0; off >>= 1) {
        if (tid < off) {
#pragma unroll
            for (int j = 0; j < 6; j++)
                red[j * 512 + tid] += red[j * 512 + tid + off];
        }
        __syncthreads();
    }
    float th[6];
#pragma unroll
    for (int j = 0; j < 6; j++) th[j] = red[j * 512] + bstn[c * 6 + j];

    // sample -> x_objT[b,c,hw(208),m]; zero-pad rows 196..207
    unsigned short* obase = x_objT + ((size_t)(b * C_CLS + c) * 208) * 64;
    for (int i = tid; i < 12 * 64; i += 512)
        obase[(size_t)(NPIX + i / 64) * 64 + (i & 63)] = 0;

    const int m = tid & 63;
    const int hwg = tid >> 6;                  // 0..7
    unsigned short* ob = obase + m;
    const float* xrow = &xs[m * 209];
    for (int it = 0; it < 25; it++) {
        int hw = hwg + it * 8;
        if (hw >= NPIX) break;                 // wave-uniform
        int h = hw / HWD, w = hw - h * HWD;
        float fx = -1.f + w * (2.f / 13.f);
        float fy = -1.f + h * (2.f / 13.f);
        float gxn = th[0] * fx + th[1] * fy + th[2];
        float gyn = th[3] * fx + th[4] * fy + th[5];
        float gx = (gxn + 1.f) * 0.5f * (HWD - 1);
        float gy = (gyn + 1.f) * 0.5f * (HWD - 1);
        float x0f = floorf(gx), y0f = floorf(gy);
        int x0 = (int)x0f, y0 = (int)y0f;
        int x1 = x0 + 1, y1 = y0 + 1;
        auto gat = [&](int yi, int xi) -> float {
            bool v = (yi >= 0) & (yi < HWD) & (xi >= 0) & (xi < HWD);
            int yc = min(max(yi, 0), HWD - 1);
            int xc = min(max(xi, 0), HWD - 1);
            return v ? xrow[yc * HWD + xc] : 0.f;
        };
        float xw1 = (float)x1 - gx, xw0 = gx - (float)x0;
        float yw1 = (float)y1 - gy, yw0 = gy - (float)y0;
        float val = gat(y0, x0) * xw1 * yw1 + gat(y0, x1) * xw0 * yw1 +
                    gat(y1, x0) * xw1 * yw0 + gat(y1, x1) * xw0 * yw0;
        ob[(size_t)hw * 64] = f2bf(val);
    }
}

// ---------------------------------------------------------------------------
// Kernel 4: relation via MFMA. Block=(k,c,b), 4 waves. NO LDS: B-fragments
// direct from x_objT (208 zero-padded rows); A cvt'd from fp32 Wg in-reg.
// ---------------------------------------------------------------------------
__global__ __launch_bounds__(256) void relation_mfma_kernel(
        const unsigned short* __restrict__ x_objT,
        const float* __restrict__ Wg,
        float* __restrict__ partial) {
    const int k = blockIdx.x;
    const int c = blockIdx.y;
    const int b = blockIdx.z;
    const int kj = (k < c) ? k : k + 1;
    const int tid = threadIdx.x;
    const int lane = tid & 63;
    const int wv = tid >> 6;
    const int l15 = lane & 15;
    const int lq = lane >> 4;

    bf16x8s AF[2][4];
    const float* wgb = Wg + (((size_t)c * K_REL + k) * U_DIM) * (2 * M_DIM);
#pragma unroll
    for (int ut = 0; ut < 2; ut++) {
        int u = wv * 32 + ut * 16 + l15;
#pragma unroll
        for (int ks = 0; ks < 4; ks++)
            AF[ut][ks] = cvt8(wgb + (size_t)u * 128 + ks * 32 + lq * 8);
    }

    const unsigned short* xc = x_objT + ((size_t)(b * C_CLS + c)) * 208 * 64;
    const unsigned short* xk = x_objT + ((size_t)(b * C_CLS + kj)) * 208 * 64;

    float csum[2][4];
#pragma unroll
    for (int ut = 0; ut < 2; ut++)
#pragma unroll
        for (int r = 0; r < 4; r++) csum[ut][r] = 0.f;

    for (int t = 0; t < 13; t++) {
        bf16x8s BF[4];
#pragma unroll
        for (int ks = 0; ks < 4; ks++) {
            const unsigned short* base = (ks < 2) ? xc : xk;
            BF[ks] = *(const bf16x8s*)(base + (size_t)(t * 16 + l15) * 64
                                       + (ks & 1) * 32 + lq * 8);
        }
        f32x4 acc0 = {0.f, 0.f, 0.f, 0.f}, acc1 = {0.f, 0.f, 0.f, 0.f};
#pragma unroll
        for (int ks = 0; ks < 4; ks++) {
            acc0 = __builtin_amdgcn_mfma_f32_16x16x32_bf16(AF[0][ks], BF[ks], acc0, 0, 0, 0);
            acc1 = __builtin_amdgcn_mfma_f32_16x16x32_bf16(AF[1][ks], BF[ks], acc1, 0, 0, 0);
        }
#pragma unroll
        for (int r = 0; r < 4; r++) {
            csum[0][r] += fmaxf(acc0[r], 0.f);
            csum[1][r] += fmaxf(acc1[r], 0.f);
        }
    }
#pragma unroll
    for (int mask = 1; mask < 16; mask <<= 1) {
#pragma unroll
        for (int ut = 0; ut < 2; ut++)
#pragma unroll
            for (int r = 0; r < 4; r++)
                csum[ut][r] += __shfl_xor(csum[ut][r], mask, 64);
    }
    if (l15 == 0) {
        float* pp = partial + (((size_t)b * C_CLS + c) * K_REL + k) * U_DIM;
#pragma unroll
        for (int ut = 0; ut < 2; ut++)
#pragma unroll
            for (int r = 0; r < 4; r++)
                pp[wv * 32 + ut * 16 + lq * 4 + r] = csum[ut][r];
    }
}

// ---------------------------------------------------------------------------
// Kernel 5: out[b,c]
// ---------------------------------------------------------------------------
__global__ __launch_bounds__(128) void final_kernel(
        const float* __restrict__ partial, const float* __restrict__ wphi,
        const float* __restrict__ bphi, float* __restrict__ out) {
    int bc = blockIdx.x;
    int u = threadIdx.x;
    float s = 0.f;
    for (int k = 0; k < K_REL; k++)
        s += partial[((size_t)bc * K_REL + k) * U_DIM + u];
    s *= wphi[u];
    __shared__ float red[128];
    red[u] = s;
    __syncthreads();
    for (int off = 64; off > 0; off >>= 1) {
        if (u < off) red[u] += red[u + off];
        __syncthreads();
    }
    if (u == 0) out[bc] = red[0] / (float)NPIX + bphi[0];
}

// ---------------------------------------------------------------------------
extern "C" void kernel_launch(void* const* d_in, const int* in_sizes, int n_in,
                              void* d_out, int out_size, void* d_ws, size_t ws_size,
                              hipStream_t stream) {
    const float* x    = (const float*)d_in[0];
    const float* Wp   = (const float*)d_in[1];
    const float* Wstn = (const float*)d_in[2];
    const float* bstn = (const float*)d_in[3];
    const float* Wg   = (const float*)d_in[4];
    const float* wphi = (const float*)d_in[5];
    const float* bphi = (const float*)d_in[6];
    float* out = (float*)d_out;
    char* wsb = (char*)d_ws;

    unsigned short* xts    = (unsigned short*)(wsb);              //  3,407,872 B
    unsigned short* Awp    = (unsigned short*)(wsb + 3407872);    //  5,242,880 B
    float* xsp             = (float*)(wsb + 8650752);             // 17,039,360 B
    unsigned short* x_objT = (unsigned short*)(wsb + 25690112);   //  2,129,920 B
    float* partial         = (float*)(wsb + 27820032);            //    778,240 B
    // total 28,598,272 B

    prep_kernel<<<288, 256, 0, stream>>>(x, Wp, xts, Awp);
    gemm_kernel<<<dim3(C_CLS, B_SZ, 4), 256, 0, stream>>>(xts, Awp, xsp);
    phases_kernel<<<dim3(C_CLS, B_SZ), 512, 0, stream>>>(xsp, Wstn, bstn, x_objT);
    relation_mfma_kernel<<<dim3(K_REL, C_CLS, B_SZ), 256, 0, stream>>>(x_objT, Wg, partial);
    final_kernel<<<80, 128, 0, stream>>>(partial, wphi, bphi, out);
}

// Round 9
// 64.621 us; speedup vs baseline: 1.5478x; 1.5478x over previous
//
#include <hip/hip_runtime.h>

#define FEAT 2048
#define HWD 14
#define NPIX 196          // 14*14
#define C_CLS 20
#define M_DIM 64
#define U_DIM 128
#define B_SZ 4
#define K_REL 19          // C-1
#define NPOOL 49          // 7*7

typedef __attribute__((ext_vector_type(8))) short bf16x8s;
typedef __attribute__((ext_vector_type(8))) unsigned short ushort8v;
typedef __attribute__((ext_vector_type(4))) float f32x4;
typedef __attribute__((ext_vector_type(4))) unsigned int uint4v;

__device__ inline unsigned short f2bf(float f) {
    unsigned u = __builtin_bit_cast(unsigned, f);
    unsigned r = (u + 0x7FFF + ((u >> 16) & 1)) >> 16;   // RNE
    return (unsigned short)r;
}

__device__ inline bf16x8s cvt8(const float* __restrict__ p) {
    float4 lo = *(const float4*)p;
    float4 hi = *(const float4*)(p + 4);
    bf16x8s r;
    r[0] = (short)f2bf(lo.x); r[1] = (short)f2bf(lo.y);
    r[2] = (short)f2bf(lo.z); r[3] = (short)f2bf(lo.w);
    r[4] = (short)f2bf(hi.x); r[5] = (short)f2bf(hi.y);
    r[6] = (short)f2bf(hi.z); r[7] = (short)f2bf(hi.w);
    return r;
}

// ---------------------------------------------------------------------------
// Kernel 1: prep.
//  blocks 0..127: x -> xts (B-fragment order, 208-row zero-pad)
//  blocks 128..287: Wp -> Awp (gemm A-fragment order)
//  blocks 288..447: Wg -> Awg (relation A-fragment order):
//     row r = (c*19+k)*32 + wv*8 + ut*4 + ks; lane data = Wg[ck][u][mm..mm+7]
//     u = wv*32+ut*16+(lane&15), mm = ks*32+(lane>>4)*8
// ---------------------------------------------------------------------------
__global__ __launch_bounds__(256) void prep_kernel(
        const float* __restrict__ x, const float* __restrict__ Wp,
        const float* __restrict__ Wg,
        unsigned short* __restrict__ xts, unsigned short* __restrict__ Awp,
        unsigned short* __restrict__ Awg) {
    __shared__ unsigned short T[64][210];
    const int blk = blockIdx.x;
    const int tid = threadIdx.x;
    if (blk < 128) {
        const int b = blk >> 5;
        const int s = blk & 31;
        const float* xb = x + ((size_t)b * FEAT + s * 64) * NPIX;
        for (int i = tid; i < 64 * NPIX; i += 256) {
            int kk = i / NPIX, hw = i - kk * NPIX;
            T[kk][hw] = f2bf(xb[(size_t)kk * NPIX + hw]);
        }
        __syncthreads();
        unsigned short* ob = xts + ((size_t)(b * 32 + s)) * 1664 * 8;
        for (int i = tid; i < 1664; i += 256) {
            int ch = i / 208, row = i - ch * 208;
            ushort8v o;
#pragma unroll
            for (int j = 0; j < 8; j++)
                o[j] = (row < NPIX) ? T[ch * 8 + j][row] : (unsigned short)0;
            *(ushort8v*)(ob + (size_t)i * 8) = o;
        }
    } else if (blk < 288) {
        const int lane = tid & 63;
        // Awp: 5120 rows (c:20 x s:32 x fi:8), one row per wave, 640 waves
        int gw = (blk - 128) * 4 + (tid >> 6);
        for (int r = gw; r < 5120; r += 160 * 4) {
            int c = r >> 8;
            int rem = r & 255;
            int s = rem >> 3, fi = rem & 7;
            int rt = fi >> 1, f = fi & 1;
            int m = rt * 16 + (lane & 15);
            int k = s * 64 + f * 32 + (lane >> 4) * 8;
            bf16x8s v = cvt8(Wp + ((size_t)(c * M_DIM + m)) * FEAT + k);
            *(bf16x8s*)(Awp + ((size_t)r * 64 + lane) * 8) = v;
        }
    } else {
        const int lane = tid & 63;
        // Awg: 12160 rows (ck:380 x wv:4 x fi:8), one row per wave
        int gw = (blk - 288) * 4 + (tid >> 6);
        for (int r = gw; r < 12160; r += 160 * 4) {
            int ck = r >> 5;
            int rem = r & 31;
            int wv = rem >> 3, fi = rem & 7;
            int ut = fi >> 2, ks = fi & 3;
            int u = wv * 32 + ut * 16 + (lane & 15);
            int mm = ks * 32 + (lane >> 4) * 8;
            bf16x8s v = cvt8(Wg + ((size_t)ck * U_DIM + u) * 128 + mm);
            *(bf16x8s*)(Awg + ((size_t)r * 64 + lane) * 8) = v;
        }
    }
}

// ---------------------------------------------------------------------------
// Kernel 2: GEMM, K-split 4. Block=(c,b,ks): 64x208 x K=512 slice.
// 4 waves = pure column split, col-tiles {4,3,3,3}. No LDS, no barriers;
// A/B fragments direct from pre-swizzled global, depth-1 named prefetch.
// Writes fp32 partial xsp[ks][b][c][64][208] (no atomics).
// ---------------------------------------------------------------------------
__global__ __launch_bounds__(256) void gemm_kernel(
        const unsigned short* __restrict__ xts,
        const unsigned short* __restrict__ Awp,
        float* __restrict__ xsp) {
    const int c = blockIdx.x, b = blockIdx.y, ks = blockIdx.z;
    const int tid = threadIdx.x;
    const int lane = tid & 63, wv = tid >> 6;
    const int l15 = lane & 15, lq = lane >> 4;
    const int t0 = (wv == 0) ? 0 : (3 * wv + 1);   // {0,4,7,10}
    const int nt = (wv == 0) ? 4 : 3;

    const unsigned short* xsrc = xts + (size_t)b * 32 * 1664 * 8;
    const unsigned short* asrc = Awp + (size_t)c * 256 * 64 * 8;
    const int s0 = ks * 8;

    bf16x8s A0[8], A1[8], B0[8], B1[8];
    auto aload = [&](int s, bf16x8s (&A)[8]) {
#pragma unroll
        for (int fi = 0; fi < 8; fi++)
            A[fi] = *(const bf16x8s*)(asrc + (((size_t)s * 8 + fi) * 64 + lane) * 8);
    };
    auto bload = [&](int s, bf16x8s (&B)[8]) {
#pragma unroll
        for (int q = 0; q < 4; q++) {
            if (q < nt) {
#pragma unroll
                for (int f = 0; f < 2; f++)
                    B[q * 2 + f] = *(const bf16x8s*)(xsrc +
                        ((size_t)s * 1664 + (f * 4 + lq) * 208 + (t0 + q) * 16 + l15) * 8);
            }
        }
    };

    f32x4 acc[4][4];   // [col-tile q][row-frag rt]
#pragma unroll
    for (int q = 0; q < 4; q++)
#pragma unroll
        for (int rt = 0; rt < 4; rt++) acc[q][rt] = (f32x4){0.f, 0.f, 0.f, 0.f};

    auto compute = [&](bf16x8s (&A)[8], bf16x8s (&B)[8]) {
#pragma unroll
        for (int q = 0; q < 4; q++) {
            if (q < nt) {
#pragma unroll
                for (int rt = 0; rt < 4; rt++)
#pragma unroll
                    for (int f = 0; f < 2; f++)
                        acc[q][rt] = __builtin_amdgcn_mfma_f32_16x16x32_bf16(
                            A[rt * 2 + f], B[q * 2 + f], acc[q][rt], 0, 0, 0);
            }
        }
    };

    aload(s0, A0); bload(s0, B0);
#pragma unroll
    for (int sp = 0; sp < 4; sp++) {
        aload(s0 + 2 * sp + 1, A1); bload(s0 + 2 * sp + 1, B1);
        compute(A0, B0);
        if (sp < 3) { aload(s0 + 2 * sp + 2, A0); bload(s0 + 2 * sp + 2, B0); }
        compute(A1, B1);
    }

    float* ob = xsp + ((size_t)(ks * B_SZ + b) * C_CLS + c) * 64 * 208;
#pragma unroll
    for (int q = 0; q < 4; q++) {
        if (q < nt) {
            int tt = t0 + q;
#pragma unroll
            for (int rt = 0; rt < 4; rt++)
#pragma unroll
                for (int r = 0; r < 4; r++)
                    ob[(rt * 16 + lq * 4 + r) * 208 + tt * 16 + l15] = acc[q][rt][r];
        }
    }
}

// ---------------------------------------------------------------------------
// Kernel 3: phases. Block=(c,b), 512 thr. Sum 4 K-partials -> xs LDS,
// then pool -> theta -> bilinear sample -> x_objT (208 rows, 196..207 = 0).
// ---------------------------------------------------------------------------
__global__ __launch_bounds__(512) void phases_kernel(
        const float* __restrict__ xsp,
        const float* __restrict__ Wstn,
        const float* __restrict__ bstn,
        unsigned short* __restrict__ x_objT) {
    __shared__ __align__(16) char smem[78336];
    float* xs     = (float*)smem;              // [64][209] = 53,504 B
    float* pooled = (float*)(smem + 53504);    // [3136]    = 12,544 B
    float* red    = (float*)(smem + 66048);    // [6][512]  = 12,288 B

    const int c = blockIdx.x, b = blockIdx.y;
    const int tid = threadIdx.x;

    // sum 4 K-split partials
    const size_t S = (size_t)B_SZ * C_CLS * 13312;   // per-ks stride
    const float* pb = xsp + (size_t)(b * C_CLS + c) * 13312;
#pragma unroll 2
    for (int it = 0; it < 26; it++) {
        int i = tid + it * 512;                      // 26*512 = 13312 exact
        float v = pb[i] + pb[i + S] + pb[i + 2 * S] + pb[i + 3 * S];
        xs[(i / 208) * 209 + (i % 208)] = v;
    }
    __syncthreads();

    // pool
    for (int i = tid; i < 3136; i += 512) {
        int m = i / NPOOL, p = i - m * NPOOL;
        int ph = p / 7, pw = p - ph * 7;
        const float* bp = &xs[m * 209 + ph * 2 * HWD + pw * 2];
        float v = fmaxf(fmaxf(bp[0], bp[1]), fmaxf(bp[HWD], bp[HWD + 1]));
        pooled[i] = fmaxf(v, 0.f);
    }
    __syncthreads();

    // theta
    float sj[6] = {0, 0, 0, 0, 0, 0};
#pragma unroll
    for (int it = 0; it < 7; it++) {
        int kk = tid + it * 512;
        if (kk < 3136) {
            float f = pooled[kk];
#pragma unroll
            for (int j = 0; j < 6; j++)
                sj[j] += f * Wstn[((size_t)c * 6 + j) * 3136 + kk];
        }
    }
#pragma unroll
    for (int j = 0; j < 6; j++) red[j * 512 + tid] = sj[j];
    __syncthreads();
    for (int off = 256; off > 0; off >>= 1) {
        if (tid < off) {
#pragma unroll
            for (int j = 0; j < 6; j++)
                red[j * 512 + tid] += red[j * 512 + tid + off];
        }
        __syncthreads();
    }
    float th[6];
#pragma unroll
    for (int j = 0; j < 6; j++) th[j] = red[j * 512] + bstn[c * 6 + j];

    // sample -> x_objT[b,c,hw(208),m]; zero-pad rows 196..207
    unsigned short* obase = x_objT + ((size_t)(b * C_CLS + c) * 208) * 64;
    for (int i = tid; i < 12 * 64; i += 512)
        obase[(size_t)(NPIX + i / 64) * 64 + (i & 63)] = 0;

    const int m = tid & 63;
    const int hwg = tid >> 6;                  // 0..7
    unsigned short* ob = obase + m;
    const float* xrow = &xs[m * 209];
    for (int it = 0; it < 25; it++) {
        int hw = hwg + it * 8;
        if (hw >= NPIX) break;                 // wave-uniform
        int h = hw / HWD, w = hw - h * HWD;
        float fx = -1.f + w * (2.f / 13.f);
        float fy = -1.f + h * (2.f / 13.f);
        float gxn = th[0] * fx + th[1] * fy + th[2];
        float gyn = th[3] * fx + th[4] * fy + th[5];
        float gx = (gxn + 1.f) * 0.5f * (HWD - 1);
        float gy = (gyn + 1.f) * 0.5f * (HWD - 1);
        float x0f = floorf(gx), y0f = floorf(gy);
        int x0 = (int)x0f, y0 = (int)y0f;
        int x1 = x0 + 1, y1 = y0 + 1;
        auto gat = [&](int yi, int xi) -> float {
            bool v = (yi >= 0) & (yi < HWD) & (xi >= 0) & (xi < HWD);
            int yc = min(max(yi, 0), HWD - 1);
            int xc = min(max(xi, 0), HWD - 1);
            return v ? xrow[yc * HWD + xc] : 0.f;
        };
        float xw1 = (float)x1 - gx, xw0 = gx - (float)x0;
        float yw1 = (float)y1 - gy, yw0 = gy - (float)y0;
        float val = gat(y0, x0) * xw1 * yw1 + gat(y0, x1) * xw0 * yw1 +
                    gat(y1, x0) * xw1 * yw0 + gat(y1, x1) * xw0 * yw0;
        ob[(size_t)hw * 64] = f2bf(val);
    }
}

// ---------------------------------------------------------------------------
// Kernel 4: relation via MFMA. Block=(k,c,b), 4 waves. X staged in LDS
// (coalesced, zero-padded source). A-fragments from pre-swizzled bf16 Awg
// (8 contiguous 1KB wave-loads).
// ---------------------------------------------------------------------------
#define MP 136
__global__ __launch_bounds__(256) void relation_mfma_kernel(
        const unsigned short* __restrict__ x_objT,
        const unsigned short* __restrict__ Awg,
        float* __restrict__ partial) {
    __shared__ unsigned short Xs[208 * MP];   // 56,576 B
    const int k = blockIdx.x;
    const int c = blockIdx.y;
    const int b = blockIdx.z;
    const int kj = (k < c) ? k : k + 1;
    const int tid = threadIdx.x;
    const int lane = tid & 63;
    const int wv = tid >> 6;
    const int l15 = lane & 15;
    const int lq = lane >> 4;

    // A-fragments: 8 contiguous wave-loads from Awg
    bf16x8s AF[2][4];
    const unsigned short* ab = Awg + (((size_t)(c * K_REL + k) * 4 + wv) * 8 * 64) * 8;
#pragma unroll
    for (int ut = 0; ut < 2; ut++)
#pragma unroll
        for (int ks = 0; ks < 4; ks++)
            AF[ut][ks] = *(const bf16x8s*)(ab + ((size_t)(ut * 4 + ks) * 64 + lane) * 8);

    // Stage Xs[hw][m']: 208 rows x 16 chunks (ch<8: xc, ch>=8: xk); no bounds
    const unsigned short* xc = x_objT + ((size_t)(b * C_CLS + c)) * 208 * 64;
    const unsigned short* xk = x_objT + ((size_t)(b * C_CLS + kj)) * 208 * 64;
#pragma unroll
    for (int it = 0; it < 13; it++) {
        int i = tid + it * 256;            // 0..3327
        int hw = i >> 4, ch = i & 15;
        const unsigned short* src = (ch < 8 ? xc : xk) + (size_t)hw * 64 + (ch & 7) * 8;
        *(uint4v*)(&Xs[hw * MP + ch * 8]) = *(const uint4v*)src;
    }
    __syncthreads();

    float csum[2][4];
#pragma unroll
    for (int ut = 0; ut < 2; ut++)
#pragma unroll
        for (int r = 0; r < 4; r++) csum[ut][r] = 0.f;

    for (int t = 0; t < 13; t++) {
        bf16x8s BF[4];
#pragma unroll
        for (int ks = 0; ks < 4; ks++)
            BF[ks] = *(const bf16x8s*)(&Xs[(t * 16 + l15) * MP + ks * 32 + lq * 8]);
        f32x4 acc0 = {0.f, 0.f, 0.f, 0.f}, acc1 = {0.f, 0.f, 0.f, 0.f};
#pragma unroll
        for (int ks = 0; ks < 4; ks++) {
            acc0 = __builtin_amdgcn_mfma_f32_16x16x32_bf16(AF[0][ks], BF[ks], acc0, 0, 0, 0);
            acc1 = __builtin_amdgcn_mfma_f32_16x16x32_bf16(AF[1][ks], BF[ks], acc1, 0, 0, 0);
        }
#pragma unroll
        for (int r = 0; r < 4; r++) {
            csum[0][r] += fmaxf(acc0[r], 0.f);
            csum[1][r] += fmaxf(acc1[r], 0.f);
        }
    }
#pragma unroll
    for (int mask = 1; mask < 16; mask <<= 1) {
#pragma unroll
        for (int ut = 0; ut < 2; ut++)
#pragma unroll
            for (int r = 0; r < 4; r++)
                csum[ut][r] += __shfl_xor(csum[ut][r], mask, 64);
    }
    if (l15 == 0) {
        float* pp = partial + (((size_t)b * C_CLS + c) * K_REL + k) * U_DIM;
#pragma unroll
        for (int ut = 0; ut < 2; ut++)
#pragma unroll
            for (int r = 0; r < 4; r++)
                pp[wv * 32 + ut * 16 + lq * 4 + r] = csum[ut][r];
    }
}

// ---------------------------------------------------------------------------
// Kernel 5: out[b,c]
// ---------------------------------------------------------------------------
__global__ __launch_bounds__(128) void final_kernel(
        const float* __restrict__ partial, const float* __restrict__ wphi,
        const float* __restrict__ bphi, float* __restrict__ out) {
    int bc = blockIdx.x;
    int u = threadIdx.x;
    float s = 0.f;
    for (int k = 0; k < K_REL; k++)
        s += partial[((size_t)bc * K_REL + k) * U_DIM + u];
    s *= wphi[u];
    __shared__ float red[128];
    red[u] = s;
    __syncthreads();
    for (int off = 64; off > 0; off >>= 1) {
        if (u < off) red[u] += red[u + off];
        __syncthreads();
    }
    if (u == 0) out[bc] = red[0] / (float)NPIX + bphi[0];
}

// ---------------------------------------------------------------------------
extern "C" void kernel_launch(void* const* d_in, const int* in_sizes, int n_in,
                              void* d_out, int out_size, void* d_ws, size_t ws_size,
                              hipStream_t stream) {
    const float* x    = (const float*)d_in[0];
    const float* Wp   = (const float*)d_in[1];
    const float* Wstn = (const float*)d_in[2];
    const float* bstn = (const float*)d_in[3];
    const float* Wg   = (const float*)d_in[4];
    const float* wphi = (const float*)d_in[5];
    const float* bphi = (const float*)d_in[6];
    float* out = (float*)d_out;
    char* wsb = (char*)d_ws;

    unsigned short* xts    = (unsigned short*)(wsb);              //  3,407,872 B
    unsigned short* Awp    = (unsigned short*)(wsb + 3407872);    //  5,242,880 B
    unsigned short* Awg    = (unsigned short*)(wsb + 8650752);    // 12,451,840 B
    float* xsp             = (float*)(wsb + 21102592);            // 17,039,360 B
    unsigned short* x_objT = (unsigned short*)(wsb + 38141952);   //  2,129,920 B
    float* partial         = (float*)(wsb + 40271872);            //    778,240 B
    // total 41,050,112 B

    prep_kernel<<<448, 256, 0, stream>>>(x, Wp, Wg, xts, Awp, Awg);
    gemm_kernel<<<dim3(C_CLS, B_SZ, 4), 256, 0, stream>>>(xts, Awp, xsp);
    phases_kernel<<<dim3(C_CLS, B_SZ), 512, 0, stream>>>(xsp, Wstn, bstn, x_objT);
    relation_mfma_kernel<<<dim3(K_REL, C_CLS, B_SZ), 256, 0, stream>>>(x_objT, Awg, partial);
    final_kernel<<<80, 128, 0, stream>>>(partial, wphi, bphi, out);
}